// Round 1
// baseline (889.903 us; speedup 1.0000x reference)
//
#include <hip/hip_runtime.h>
#include <hip/hip_bf16.h>
#include <stdint.h>

// Problem constants (from reference):
#define N_NODES 262144
#define DDIM 128      // embed dim
#define KDIM 256      // 2*D (concat input)
#define HDIM 256      // hidden
#define NTYPE 4
#define BM 64         // rows (nodes) per block in the MLP kernel

typedef float  f32x4  __attribute__((ext_vector_type(4)));
typedef short  bf16x8 __attribute__((ext_vector_type(8)));
typedef unsigned short u16x4 __attribute__((ext_vector_type(4)));

// ws int-meta layout: [0..3]=counts  [4..8]=off[0..4]  [9..13]=tileoff[0..4]  [14..17]=cursors

__device__ __forceinline__ unsigned short f2b(float v) {
    // f32 -> bf16 round-to-nearest-even (finite inputs only)
    unsigned int u = __builtin_bit_cast(unsigned int, v);
    u += 0x7FFFu + ((u >> 16) & 1u);
    return (unsigned short)(u >> 16);
}

// ---------------- K1: zero meta + convert/transpose weights to bf16 ----------------
__global__ void k_prep(const float* __restrict__ W1, const float* __restrict__ W2,
                       int* __restrict__ meta,
                       unsigned short* __restrict__ W1T, unsigned short* __restrict__ W2T) {
    int tid = blockIdx.x * blockDim.x + threadIdx.x;
    if (blockIdx.x == 0 && threadIdx.x < 32) meta[threadIdx.x] = 0;
    const int n1 = NTYPE * HDIM * KDIM;   // W1T[t][h][k] = W1[t][k][h]
    for (int i = tid; i < n1; i += gridDim.x * blockDim.x) {
        int t = i / (HDIM * KDIM);
        int rem = i % (HDIM * KDIM);
        int hh = rem / KDIM;
        int k  = rem % KDIM;
        W1T[i] = f2b(W1[((size_t)t * KDIM + k) * HDIM + hh]);
    }
    const int n2 = NTYPE * DDIM * HDIM;   // W2T[t][d][k] = W2[t][k][d]
    for (int i = tid; i < n2; i += gridDim.x * blockDim.x) {
        int t = i / (DDIM * HDIM);
        int rem = i % (DDIM * HDIM);
        int d = rem / HDIM;
        int k = rem % HDIM;
        W2T[i] = f2b(W2[((size_t)t * HDIM + k) * DDIM + d]);
    }
}

// ---------------- K2: per-type histogram (wave-aggregated atomics) ----------------
__global__ void k_hist(const int* __restrict__ ids, int* __restrict__ meta) {
    int i = blockIdx.x * 256 + threadIdx.x;
    int t = ids[i];
    int lane = threadIdx.x & 63;
    #pragma unroll
    for (int tt = 0; tt < NTYPE; ++tt) {
        unsigned long long m = __ballot(t == tt);
        if (m) {
            int leader = __ffsll((unsigned long long)m) - 1;
            if (lane == leader) atomicAdd(&meta[tt], (int)__popcll(m));
        }
    }
}

// ---------------- K3: tiny serial scan ----------------
__global__ void k_scan(int* __restrict__ meta) {
    if (threadIdx.x == 0 && blockIdx.x == 0) {
        int off = 0, toff = 0;
        for (int t = 0; t < NTYPE; ++t) {
            int c = meta[t];
            meta[4 + t]  = off;   // segment start
            meta[9 + t]  = toff;  // tile start
            meta[14 + t] = off;   // scatter cursor
            off  += c;
            toff += (c + BM - 1) / BM;
        }
        meta[8]  = off;   // == N
        meta[13] = toff;  // total tiles
    }
}

// ---------------- K4: scatter node indices into type-sorted perm ----------------
__global__ void k_scatter(const int* __restrict__ ids, int* __restrict__ meta,
                          int* __restrict__ perm) {
    int i = blockIdx.x * 256 + threadIdx.x;
    int t = ids[i];
    int lane = threadIdx.x & 63;
    #pragma unroll
    for (int tt = 0; tt < NTYPE; ++tt) {
        unsigned long long m = __ballot(t == tt);
        if (m) {
            int leader = __ffsll((unsigned long long)m) - 1;
            int base = 0;
            if (lane == leader) base = atomicAdd(&meta[14 + tt], (int)__popcll(m));
            base = __shfl(base, leader, 64);
            if (t == tt) {
                int rank = (int)__popcll(m & ((1ull << lane) - 1ull));
                perm[base + rank] = i;
            }
        }
    }
}

// ---------------- K5: the fused 2-layer MLP (single-type blocks, MFMA) ----------------
// Block: 256 thr (4 waves). BM=64 nodes. Wave w owns H-cols [64w,64w+64) in GEMM1,
// D-cols [32w,32w+32) in GEMM2. X and hidden activations share one 32KB LDS buffer,
// XOR-swizzled (byte ^= (row&7)<<4) to kill the stride-512B bank conflict on ds_read_b128.
__global__ __launch_bounds__(256) void k_mlp(
        const float* __restrict__ hbuf, const float* __restrict__ mbuf,
        const float* __restrict__ b1,   const float* __restrict__ b2,
        const int* __restrict__ meta,   const int* __restrict__ perm,
        const unsigned short* __restrict__ W1T, const unsigned short* __restrict__ W2T,
        float* __restrict__ dh) {
    __shared__ unsigned short lds[BM * KDIM];  // 32 KB; X for GEMM1, then silu acts for GEMM2
    __shared__ int pm[BM];
    __shared__ int sseg[3];

    int b = blockIdx.x;
    if (threadIdx.x == 0) {
        if (b >= meta[13]) {
            sseg[0] = -1;
        } else {
            int t = 0;
            while (b >= meta[9 + t + 1]) ++t;      // t in [0,3]
            sseg[0] = t;
            sseg[1] = meta[4 + t] + (b - meta[9 + t]) * BM;  // row0 in sorted order
            sseg[2] = meta[4 + t + 1];                        // segment end
        }
    }
    __syncthreads();
    int t = sseg[0];
    if (t < 0) return;
    int row0 = sseg[1], segend = sseg[2];

    if (threadIdx.x < BM) {
        int p = row0 + threadIdx.x;
        pm[threadIdx.x] = perm[p < N_NODES ? p : (N_NODES - 1)];
    }
    __syncthreads();

    // ---- stage X = bf16(concat(h[node], msg[node])) into swizzled LDS ----
    #pragma unroll
    for (int i = threadIdx.x; i < BM * 64; i += 256) {   // 64 float4-chunks per row
        int r = i >> 6, c = i & 63;
        int node = pm[r];
        const float* src = (c < 32) ? (hbuf + (size_t)node * DDIM + c * 4)
                                    : (mbuf + (size_t)node * DDIM + (c - 32) * 4);
        float4 v = *reinterpret_cast<const float4*>(src);
        u16x4 o;
        o.x = f2b(v.x); o.y = f2b(v.y); o.z = f2b(v.z); o.w = f2b(v.w);
        int soff = (r * KDIM + c * 4) ^ ((r & 7) << 3);   // short-unit offset
        *reinterpret_cast<u16x4*>(&lds[soff]) = o;
    }
    __syncthreads();

    int lane = threadIdx.x & 63;
    int w    = threadIdx.x >> 6;
    int lr   = lane & 15;   // row/col selector inside 16x16 tile
    int lg   = lane >> 4;   // k-group 0..3

    // ---- GEMM1: (64 x 256) @ W1T-slice -> hidden 64 x 64 per wave ----
    f32x4 acc[4][4];
    #pragma unroll
    for (int mt = 0; mt < 4; ++mt)
        #pragma unroll
        for (int nt = 0; nt < 4; ++nt)
            acc[mt][nt] = (f32x4){0.f, 0.f, 0.f, 0.f};

    const unsigned short* W1p = W1T + (size_t)t * HDIM * KDIM;
    #pragma unroll
    for (int kt = 0; kt < KDIM / 32; ++kt) {
        int kk = kt * 32 + lg * 8;
        bf16x8 a[4], bb[4];
        #pragma unroll
        for (int mt = 0; mt < 4; ++mt) {
            int r = mt * 16 + lr;
            int soff = (r * KDIM + kk) ^ ((r & 7) << 3);
            a[mt] = *reinterpret_cast<const bf16x8*>(&lds[soff]);
        }
        #pragma unroll
        for (int nt = 0; nt < 4; ++nt) {
            int hrow = w * 64 + nt * 16 + lr;
            bb[nt] = *reinterpret_cast<const bf16x8*>(W1p + (size_t)hrow * KDIM + kk);
        }
        #pragma unroll
        for (int mt = 0; mt < 4; ++mt)
            #pragma unroll
            for (int nt = 0; nt < 4; ++nt)
                acc[mt][nt] = __builtin_amdgcn_mfma_f32_16x16x32_bf16(a[mt], bb[nt], acc[mt][nt], 0, 0, 0);
    }

    __syncthreads();   // all X reads done before overwriting LDS with activations

    // ---- bias + SiLU, write hidden activations (bf16) back to swizzled LDS ----
    #pragma unroll
    for (int nt = 0; nt < 4; ++nt) {
        int hcol = w * 64 + nt * 16 + lr;
        float b1v = b1[t * HDIM + hcol];
        #pragma unroll
        for (int mt = 0; mt < 4; ++mt) {
            #pragma unroll
            for (int r4 = 0; r4 < 4; ++r4) {
                int row = mt * 16 + lg * 4 + r4;
                float z = acc[mt][nt][r4] + b1v;
                float s = z / (1.f + __expf(-z));
                int soff = (row * KDIM + hcol) ^ ((row & 7) << 3);
                lds[soff] = f2b(s);
            }
        }
    }
    __syncthreads();

    // ---- GEMM2: (64 x 256) @ W2T-slice -> out 64 x 32 per wave ----
    f32x4 acc2[4][2];
    #pragma unroll
    for (int mt = 0; mt < 4; ++mt)
        #pragma unroll
        for (int nt = 0; nt < 2; ++nt)
            acc2[mt][nt] = (f32x4){0.f, 0.f, 0.f, 0.f};

    const unsigned short* W2p = W2T + (size_t)t * DDIM * HDIM;
    #pragma unroll
    for (int kt = 0; kt < HDIM / 32; ++kt) {
        int kk = kt * 32 + lg * 8;
        bf16x8 a[4], bb[2];
        #pragma unroll
        for (int mt = 0; mt < 4; ++mt) {
            int r = mt * 16 + lr;
            int soff = (r * KDIM + kk) ^ ((r & 7) << 3);
            a[mt] = *reinterpret_cast<const bf16x8*>(&lds[soff]);
        }
        #pragma unroll
        for (int nt = 0; nt < 2; ++nt) {
            int drow = w * 32 + nt * 16 + lr;
            bb[nt] = *reinterpret_cast<const bf16x8*>(W2p + (size_t)drow * HDIM + kk);
        }
        #pragma unroll
        for (int mt = 0; mt < 4; ++mt)
            #pragma unroll
            for (int nt = 0; nt < 2; ++nt)
                acc2[mt][nt] = __builtin_amdgcn_mfma_f32_16x16x32_bf16(a[mt], bb[nt], acc2[mt][nt], 0, 0, 0);
    }

    // ---- epilogue: + b2, scatter rows to dh[node] ----
    #pragma unroll
    for (int nt = 0; nt < 2; ++nt) {
        int d = w * 32 + nt * 16 + lr;
        float b2v = b2[t * DDIM + d];
        #pragma unroll
        for (int mt = 0; mt < 4; ++mt) {
            #pragma unroll
            for (int r4 = 0; r4 < 4; ++r4) {
                int row = mt * 16 + lg * 4 + r4;
                int p = row0 + row;
                if (p < segend) {
                    dh[(size_t)pm[row] * DDIM + d] = acc2[mt][nt][r4] + b2v;
                }
            }
        }
    }
}

extern "C" void kernel_launch(void* const* d_in, const int* in_sizes, int n_in,
                              void* d_out, int out_size, void* d_ws, size_t ws_size,
                              hipStream_t stream) {
    const float* h   = (const float*)d_in[0];
    const float* msg = (const float*)d_in[1];
    const int*   ids = (const int*)d_in[2];
    const float* W1  = (const float*)d_in[3];
    const float* b1  = (const float*)d_in[4];
    const float* W2  = (const float*)d_in[5];
    const float* b2  = (const float*)d_in[6];
    float* dh = (float*)d_out;

    char* ws = (char*)d_ws;
    int* meta = (int*)ws;
    int* perm = (int*)(ws + 128);
    unsigned short* W1T = (unsigned short*)(ws + 128 + (size_t)N_NODES * 4);
    unsigned short* W2T = W1T + (size_t)NTYPE * HDIM * KDIM;

    k_prep<<<512, 256, 0, stream>>>(W1, W2, meta, W1T, W2T);
    k_hist<<<N_NODES / 256, 256, 0, stream>>>(ids, meta);
    k_scan<<<1, 64, 0, stream>>>(meta);
    k_scatter<<<N_NODES / 256, 256, 0, stream>>>(ids, meta, perm);
    k_mlp<<<N_NODES / BM + 4, 256, 0, stream>>>(h, msg, b1, b2, meta, perm, W1T, W2T, dh);
}

// Round 2
// 451.912 us; speedup vs baseline: 1.9692x; 1.9692x over previous
//
#include <hip/hip_runtime.h>
#include <hip/hip_bf16.h>
#include <stdint.h>

#define N_NODES 262144
#define DDIM 128      // embed dim
#define KDIM 256      // 2*D concat input
#define HDIM 256      // hidden
#define NTYPE 4
#define BM 64         // nodes per MLP block
#define NB 1024       // N/256 histogram blocks

typedef float  f32x4  __attribute__((ext_vector_type(4)));
typedef short  bf16x8 __attribute__((ext_vector_type(8)));
typedef unsigned short u16x4 __attribute__((ext_vector_type(4)));

// meta layout: [4..7]=seg off[t], [8]=N, [9..12]=tile off[t], [13]=total tiles

__device__ __forceinline__ unsigned short f2b(float v) {
    unsigned int u = __builtin_bit_cast(unsigned int, v);
    u += 0x7FFFu + ((u >> 16) & 1u);
    return (unsigned short)(u >> 16);
}

// ---------------- K1: convert/transpose weights to bf16 ----------------
__global__ void k_prep(const float* __restrict__ W1, const float* __restrict__ W2,
                       unsigned short* __restrict__ W1T, unsigned short* __restrict__ W2T) {
    int tid = blockIdx.x * blockDim.x + threadIdx.x;
    const int n1 = NTYPE * HDIM * KDIM;   // W1T[t][h][k] = W1[t][k][h]
    for (int i = tid; i < n1; i += gridDim.x * blockDim.x) {
        int t = i / (HDIM * KDIM);
        int rem = i % (HDIM * KDIM);
        int hh = rem / KDIM;
        int k  = rem % KDIM;
        W1T[i] = f2b(W1[((size_t)t * KDIM + k) * HDIM + hh]);
    }
    const int n2 = NTYPE * DDIM * HDIM;   // W2T[t][d][k] = W2[t][k][d]
    for (int i = tid; i < n2; i += gridDim.x * blockDim.x) {
        int t = i / (DDIM * HDIM);
        int rem = i % (DDIM * HDIM);
        int d = rem / HDIM;
        int k = rem % HDIM;
        W2T[i] = f2b(W2[((size_t)t * HDIM + k) * DDIM + d]);
    }
}

// ---------------- K2: per-block type counts (NO global atomics) ----------------
__global__ void k_hist(const int* __restrict__ ids, int* __restrict__ bcnt) {
    __shared__ int cnt[NTYPE];
    int tid = threadIdx.x, lane = tid & 63;
    if (tid < NTYPE) cnt[tid] = 0;
    __syncthreads();
    int t = ids[blockIdx.x * 256 + tid];
    #pragma unroll
    for (int tt = 0; tt < NTYPE; ++tt) {
        unsigned long long m = __ballot(t == tt);
        if (lane == 0) atomicAdd(&cnt[tt], (int)__popcll(m));
    }
    __syncthreads();
    if (tid < NTYPE) bcnt[tid * NB + blockIdx.x] = cnt[tid];
}

// ---------------- K3: scan per-block counts -> per-block bases + meta ----------------
__global__ __launch_bounds__(1024) void k_scan(const int* __restrict__ bcnt,
                                               int* __restrict__ gbase, int* __restrict__ meta) {
    __shared__ int wpart[16];
    __shared__ int ttot[NTYPE + 1];
    int tid = threadIdx.x, lane = tid & 63, wv = tid >> 6;
    if (tid == 0) ttot[0] = 0;
    for (int t = 0; t < NTYPE; ++t) {
        int v = bcnt[t * NB + tid];
        int s = v;
        #pragma unroll
        for (int d = 1; d < 64; d <<= 1) {
            int u = __shfl_up(s, d, 64);
            if (lane >= d) s += u;
        }
        if (lane == 63) wpart[wv] = s;
        __syncthreads();
        if (tid == 0) {
            int a = 0;
            for (int w = 0; w < 16; ++w) { int x = wpart[w]; wpart[w] = a; a += x; }
            ttot[t + 1] = ttot[t] + a;
        }
        __syncthreads();
        gbase[t * NB + tid] = ttot[t] + wpart[wv] + (s - v);
        __syncthreads();
    }
    if (tid == 0) {
        int off = 0, toff = 0;
        for (int t = 0; t < NTYPE; ++t) {
            int c = ttot[t + 1] - ttot[t];
            meta[4 + t] = off;
            meta[9 + t] = toff;
            off  += c;
            toff += (c + BM - 1) / BM;
        }
        meta[8]  = off;    // == N  (also serves as seg-end for t=3)
        meta[13] = toff;   // total tiles (also tile-end for t=3)
    }
}

// ---------------- K4: rank-based scatter (NO global atomics) ----------------
__global__ void k_scatter(const int* __restrict__ ids, const int* __restrict__ gbase,
                          int* __restrict__ perm) {
    __shared__ int wb[4][NTYPE];   // [wave][type] -> count, then exclusive offset
    int tid = threadIdx.x, lane = tid & 63, wv = tid >> 6;
    int i = blockIdx.x * 256 + tid;
    int t = ids[i];
    #pragma unroll
    for (int tt = 0; tt < NTYPE; ++tt) {
        unsigned long long m = __ballot(t == tt);
        if (lane == 0) wb[wv][tt] = (int)__popcll(m);
    }
    __syncthreads();
    if (tid < NTYPE) {
        int a = 0;
        for (int w = 0; w < 4; ++w) { int x = wb[w][tid]; wb[w][tid] = a; a += x; }
    }
    __syncthreads();
    #pragma unroll
    for (int tt = 0; tt < NTYPE; ++tt) {
        unsigned long long m = __ballot(t == tt);
        if (t == tt) {
            int rank = (int)__popcll(m & ((1ull << lane) - 1ull));
            perm[gbase[tt * NB + blockIdx.x] + wb[wv][tt] + rank] = i;
        }
    }
}

// ---------------- K5: fused 2-layer MLP (swapped-operand MFMA) ----------------
// 256 thr / 4 waves, BM=64 nodes. Operand-swapped: mfma(A=W-rows, B=X-rows) ->
// D[col=m, row=4-consecutive h (or d)] per lane -> vectorized SiLU LDS writes
// (u16x4) and vectorized epilogue stores (float4).
// LDS: single 32KB buffer, XOR-swizzled (short_off ^= (row&7)<<3), X then acts.
__global__ __launch_bounds__(256) void k_mlp(
        const float* __restrict__ hbuf, const float* __restrict__ mbuf,
        const float* __restrict__ b1,   const float* __restrict__ b2,
        const int* __restrict__ meta,   const int* __restrict__ perm,
        const unsigned short* __restrict__ W1T, const unsigned short* __restrict__ W2T,
        float* __restrict__ dh) {
    __shared__ unsigned short lds[BM * KDIM];  // exactly 32768 B

    int b = blockIdx.x;
    if (b >= meta[13]) return;
    int t = 0;
    #pragma unroll
    for (int tt = 1; tt < NTYPE; ++tt) t += (b >= meta[9 + tt]);
    int row0   = meta[4 + t] + (b - meta[9 + t]) * BM;
    int segend = meta[4 + t + 1];   // meta[8] for t=3

    int tid = threadIdx.x, lane = tid & 63, w = tid >> 6;
    int lr = lane & 15, lg = lane >> 4;

    // ---- stage X = bf16(concat(h,msg)) into swizzled LDS; one row per wave-iter ----
    int c = lane;   // 0..63 float4-chunks per row
    #pragma unroll
    for (int j = 0; j < 16; ++j) {
        int r = w + 4 * j;
        int p = row0 + r;
        int node = perm[p < N_NODES ? p : N_NODES - 1];
        const float* src = (c < 32) ? (hbuf + (size_t)node * DDIM + c * 4)
                                    : (mbuf + (size_t)node * DDIM + (c - 32) * 4);
        float4 v = *reinterpret_cast<const float4*>(src);
        u16x4 o;
        o.x = f2b(v.x); o.y = f2b(v.y); o.z = f2b(v.z); o.w = f2b(v.w);
        int soff = (r * KDIM + c * 4) ^ ((r & 7) << 3);
        *reinterpret_cast<u16x4*>(&lds[soff]) = o;
    }
    __syncthreads();

    // ---- GEMM1: D1[h][m], wave w owns h in [64w, 64w+64) ----
    f32x4 acc[4][4];
    #pragma unroll
    for (int ht = 0; ht < 4; ++ht)
        #pragma unroll
        for (int mt = 0; mt < 4; ++mt)
            acc[ht][mt] = (f32x4){0.f, 0.f, 0.f, 0.f};

    const unsigned short* W1p = W1T + (size_t)t * HDIM * KDIM + (size_t)(w * 64) * KDIM;
    #pragma unroll
    for (int kt = 0; kt < KDIM / 32; ++kt) {
        int kk = kt * 32 + lg * 8;
        bf16x8 aw[4], xb[4];
        #pragma unroll
        for (int ht = 0; ht < 4; ++ht)
            aw[ht] = *reinterpret_cast<const bf16x8*>(W1p + (size_t)(ht * 16 + lr) * KDIM + kk);
        #pragma unroll
        for (int mt = 0; mt < 4; ++mt) {
            int r = mt * 16 + lr;
            int soff = (r * KDIM + kk) ^ ((r & 7) << 3);
            xb[mt] = *reinterpret_cast<const bf16x8*>(&lds[soff]);
        }
        #pragma unroll
        for (int ht = 0; ht < 4; ++ht)
            #pragma unroll
            for (int mt = 0; mt < 4; ++mt)
                acc[ht][mt] = __builtin_amdgcn_mfma_f32_16x16x32_bf16(aw[ht], xb[mt], acc[ht][mt], 0, 0, 0);
    }
    __syncthreads();   // all X reads done before act overwrite

    // ---- bias + SiLU -> vectorized bf16x4 LDS writes (lane holds 4 consecutive h) ----
    #pragma unroll
    for (int ht = 0; ht < 4; ++ht) {
        int hcol = w * 64 + ht * 16 + lg * 4;
        f32x4 b1v = *reinterpret_cast<const f32x4*>(&b1[t * HDIM + hcol]);
        #pragma unroll
        for (int mt = 0; mt < 4; ++mt) {
            int m = mt * 16 + lr;
            u16x4 o;
            #pragma unroll
            for (int r4 = 0; r4 < 4; ++r4) {
                float z = acc[ht][mt][r4] + b1v[r4];
                float s = z / (1.f + __expf(-z));
                o[r4] = f2b(s);
            }
            int soff = (m * KDIM + hcol) ^ ((m & 7) << 3);
            *reinterpret_cast<u16x4*>(&lds[soff]) = o;
        }
    }
    __syncthreads();

    // ---- GEMM2: D2[d][m], wave w owns d in [32w, 32w+32) ----
    f32x4 acc2[2][4];
    #pragma unroll
    for (int dt = 0; dt < 2; ++dt)
        #pragma unroll
        for (int mt = 0; mt < 4; ++mt)
            acc2[dt][mt] = (f32x4){0.f, 0.f, 0.f, 0.f};

    const unsigned short* W2p = W2T + (size_t)t * DDIM * HDIM + (size_t)(w * 32) * HDIM;
    #pragma unroll
    for (int kt = 0; kt < HDIM / 32; ++kt) {
        int kk = kt * 32 + lg * 8;
        bf16x8 aw[2], ab[4];
        #pragma unroll
        for (int dt = 0; dt < 2; ++dt)
            aw[dt] = *reinterpret_cast<const bf16x8*>(W2p + (size_t)(dt * 16 + lr) * HDIM + kk);
        #pragma unroll
        for (int mt = 0; mt < 4; ++mt) {
            int m = mt * 16 + lr;
            int soff = (m * KDIM + kk) ^ ((m & 7) << 3);
            ab[mt] = *reinterpret_cast<const bf16x8*>(&lds[soff]);
        }
        #pragma unroll
        for (int dt = 0; dt < 2; ++dt)
            #pragma unroll
            for (int mt = 0; mt < 4; ++mt)
                acc2[dt][mt] = __builtin_amdgcn_mfma_f32_16x16x32_bf16(aw[dt], ab[mt], acc2[dt][mt], 0, 0, 0);
    }

    // ---- epilogue: +b2, float4 scatter (lane holds 4 consecutive d for node m) ----
    int nd[4];
    #pragma unroll
    for (int mt = 0; mt < 4; ++mt) {
        int p = row0 + mt * 16 + lr;
        nd[mt] = perm[p < N_NODES ? p : N_NODES - 1];
    }
    #pragma unroll
    for (int dt = 0; dt < 2; ++dt) {
        int d0 = w * 32 + dt * 16 + lg * 4;
        f32x4 b2v = *reinterpret_cast<const f32x4*>(&b2[t * DDIM + d0]);
        #pragma unroll
        for (int mt = 0; mt < 4; ++mt) {
            int p = row0 + mt * 16 + lr;
            if (p < segend) {
                f32x4 v = acc2[dt][mt] + b2v;
                *reinterpret_cast<f32x4*>(&dh[(size_t)nd[mt] * DDIM + d0]) = v;
            }
        }
    }
}

extern "C" void kernel_launch(void* const* d_in, const int* in_sizes, int n_in,
                              void* d_out, int out_size, void* d_ws, size_t ws_size,
                              hipStream_t stream) {
    const float* h   = (const float*)d_in[0];
    const float* msg = (const float*)d_in[1];
    const int*   ids = (const int*)d_in[2];
    const float* W1  = (const float*)d_in[3];
    const float* b1  = (const float*)d_in[4];
    const float* W2  = (const float*)d_in[5];
    const float* b2  = (const float*)d_in[6];
    float* dh = (float*)d_out;

    char* ws = (char*)d_ws;
    int* meta  = (int*)ws;                                   // 128 B
    int* perm  = (int*)(ws + 128);                           // 1 MB
    int* bcnt  = (int*)(ws + 128 + (size_t)N_NODES * 4);     // 16 KB
    int* gbase = bcnt + NTYPE * NB;                          // 16 KB
    unsigned short* W1T = (unsigned short*)(gbase + NTYPE * NB);
    unsigned short* W2T = W1T + (size_t)NTYPE * HDIM * KDIM;

    k_prep<<<512, 256, 0, stream>>>(W1, W2, W1T, W2T);
    k_hist<<<NB, 256, 0, stream>>>(ids, bcnt);
    k_scan<<<1, 1024, 0, stream>>>(bcnt, gbase, meta);
    k_scatter<<<NB, 256, 0, stream>>>(ids, gbase, perm);
    k_mlp<<<N_NODES / BM + NTYPE, 256, 0, stream>>>(h, msg, b1, b2, meta, perm, W1T, W2T, dh);
}

// Round 3
// 446.356 us; speedup vs baseline: 1.9937x; 1.0124x over previous
//
#include <hip/hip_runtime.h>
#include <hip/hip_bf16.h>
#include <stdint.h>

#define N_NODES 262144
#define DDIM 128      // embed dim
#define KDIM 256      // 2*D concat input
#define HDIM 256      // hidden
#define NTYPE 4
#define BM 64         // nodes per MLP block
#define NB 1024       // N/256 histogram blocks

typedef float  f32x4  __attribute__((ext_vector_type(4)));
typedef short  bf16x8 __attribute__((ext_vector_type(8)));
typedef unsigned short u16x4 __attribute__((ext_vector_type(4)));

// meta layout: [4..7]=seg off[t], [8]=N, [9..12]=tile off[t], [13]=total tiles

__device__ __forceinline__ unsigned short f2b(float v) {
    unsigned int u = __builtin_bit_cast(unsigned int, v);
    u += 0x7FFFu + ((u >> 16) & 1u);
    return (unsigned short)(u >> 16);
}

// ---------------- K1: fused per-block histogram + weight convert/transpose ----------------
__global__ void k_prep_hist(const int* __restrict__ ids,
                            const float* __restrict__ W1, const float* __restrict__ W2,
                            int* __restrict__ bcnt,
                            unsigned short* __restrict__ W1T, unsigned short* __restrict__ W2T) {
    __shared__ int cnt[NTYPE];
    if (blockIdx.x < NB) {
        int tid = threadIdx.x, lane = tid & 63;
        if (tid < NTYPE) cnt[tid] = 0;
        __syncthreads();
        int t = ids[blockIdx.x * 256 + tid];
        #pragma unroll
        for (int tt = 0; tt < NTYPE; ++tt) {
            unsigned long long m = __ballot(t == tt);
            if (lane == 0) atomicAdd(&cnt[tt], (int)__popcll(m));
        }
        __syncthreads();
        if (tid < NTYPE) bcnt[tid * NB + blockIdx.x] = cnt[tid];
    } else {
        int tid = (blockIdx.x - NB) * 256 + threadIdx.x;
        const int stride = 256 * 256;
        const int n1 = NTYPE * HDIM * KDIM;   // W1T[t][h][k] = W1[t][k][h]
        for (int i = tid; i < n1; i += stride) {
            int t = i / (HDIM * KDIM);
            int rem = i % (HDIM * KDIM);
            int hh = rem / KDIM;
            int k  = rem % KDIM;
            W1T[i] = f2b(W1[((size_t)t * KDIM + k) * HDIM + hh]);
        }
        const int n2 = NTYPE * DDIM * HDIM;   // W2T[t][d][k] = W2[t][k][d]
        for (int i = tid; i < n2; i += stride) {
            int t = i / (DDIM * HDIM);
            int rem = i % (DDIM * HDIM);
            int d = rem / HDIM;
            int k = rem % HDIM;
            W2T[i] = f2b(W2[((size_t)t * HDIM + k) * DDIM + d]);
        }
    }
}

// ---------------- K2: scan per-block counts -> per-block bases + meta ----------------
__global__ __launch_bounds__(1024) void k_scan(const int* __restrict__ bcnt,
                                               int* __restrict__ gbase, int* __restrict__ meta) {
    __shared__ int wpart[16];
    __shared__ int ttot[NTYPE + 1];
    int tid = threadIdx.x, lane = tid & 63, wv = tid >> 6;
    if (tid == 0) ttot[0] = 0;
    for (int t = 0; t < NTYPE; ++t) {
        int v = bcnt[t * NB + tid];
        int s = v;
        #pragma unroll
        for (int d = 1; d < 64; d <<= 1) {
            int u = __shfl_up(s, d, 64);
            if (lane >= d) s += u;
        }
        if (lane == 63) wpart[wv] = s;
        __syncthreads();
        if (tid == 0) {
            int a = 0;
            for (int w = 0; w < 16; ++w) { int x = wpart[w]; wpart[w] = a; a += x; }
            ttot[t + 1] = ttot[t] + a;
        }
        __syncthreads();
        gbase[t * NB + tid] = ttot[t] + wpart[wv] + (s - v);
        __syncthreads();
    }
    if (tid == 0) {
        int off = 0, toff = 0;
        for (int t = 0; t < NTYPE; ++t) {
            int c = ttot[t + 1] - ttot[t];
            meta[4 + t] = off;
            meta[9 + t] = toff;
            off  += c;
            toff += (c + BM - 1) / BM;
        }
        meta[8]  = off;    // == N (seg-end for t=3)
        meta[13] = toff;   // total tiles
    }
}

// ---------------- K3: rank-based scatter (no global atomics) ----------------
__global__ void k_scatter(const int* __restrict__ ids, const int* __restrict__ gbase,
                          int* __restrict__ perm) {
    __shared__ int wb[4][NTYPE];
    int tid = threadIdx.x, lane = tid & 63, wv = tid >> 6;
    int i = blockIdx.x * 256 + tid;
    int t = ids[i];
    #pragma unroll
    for (int tt = 0; tt < NTYPE; ++tt) {
        unsigned long long m = __ballot(t == tt);
        if (lane == 0) wb[wv][tt] = (int)__popcll(m);
    }
    __syncthreads();
    if (tid < NTYPE) {
        int a = 0;
        for (int w = 0; w < 4; ++w) { int x = wb[w][tid]; wb[w][tid] = a; a += x; }
    }
    __syncthreads();
    #pragma unroll
    for (int tt = 0; tt < NTYPE; ++tt) {
        unsigned long long m = __ballot(t == tt);
        if (t == tt) {
            int rank = (int)__popcll(m & ((1ull << lane) - 1ull));
            perm[gbase[tt * NB + blockIdx.x] + wb[wv][tt] + rank] = i;
        }
    }
}

// ---------------- K4: fused 2-layer MLP ----------------
// 256 thr / 4 waves, BM=64 nodes/block. Swapped-operand MFMA: D[row=4-consec h|d, col=m].
// W-fragments bulk-preloaded into registers (no per-kt L2 stalls): GEMM1 in two
// 64-VGPR half-K batches, GEMM2 in one. Separate X(32KB)/ACT(32KB) LDS buffers ->
// only 2 barriers. XOR swizzle (short_off ^= (row&7)<<3) on both buffers.
__global__ __launch_bounds__(256, 2) void k_mlp(
        const float* __restrict__ hbuf, const float* __restrict__ mbuf,
        const float* __restrict__ b1,   const float* __restrict__ b2,
        const int* __restrict__ meta,   const int* __restrict__ perm,
        const unsigned short* __restrict__ W1T, const unsigned short* __restrict__ W2T,
        float* __restrict__ dh) {
    __shared__ unsigned short xls[BM * KDIM];  // 32 KB: bf16 X tile
    __shared__ unsigned short als[BM * HDIM];  // 32 KB: bf16 activations

    int b = blockIdx.x;
    if (b >= meta[13]) return;
    int t = 0;
    #pragma unroll
    for (int tt = 1; tt < NTYPE; ++tt) t += (b >= meta[9 + tt]);
    int row0   = meta[4 + t] + (b - meta[9 + t]) * BM;
    int segend = meta[4 + t + 1];

    int tid = threadIdx.x, lane = tid & 63, w = tid >> 6;
    int lr = lane & 15, lg = lane >> 4;

    // ---- stage X = bf16(concat(h,msg)) into swizzled LDS; one row per wave-iter ----
    int c = lane;
    #pragma unroll
    for (int j = 0; j < 16; ++j) {
        int r = w + 4 * j;
        int p = row0 + r;
        int node = perm[p < N_NODES ? p : N_NODES - 1];
        const float* src = (c < 32) ? (hbuf + (size_t)node * DDIM + c * 4)
                                    : (mbuf + (size_t)node * DDIM + (c - 32) * 4);
        float4 v = *reinterpret_cast<const float4*>(src);
        u16x4 o;
        o.x = f2b(v.x); o.y = f2b(v.y); o.z = f2b(v.z); o.w = f2b(v.w);
        int soff = (r * KDIM + c * 4) ^ ((r & 7) << 3);
        *reinterpret_cast<u16x4*>(&xls[soff]) = o;
    }

    f32x4 acc[4][4];
    #pragma unroll
    for (int ht = 0; ht < 4; ++ht)
        #pragma unroll
        for (int mt = 0; mt < 4; ++mt)
            acc[ht][mt] = (f32x4){0.f, 0.f, 0.f, 0.f};

    const unsigned short* W1p = W1T + ((size_t)t * HDIM + w * 64) * KDIM;
    __syncthreads();

    // ---- GEMM1: two half-K passes, W fragments preloaded per pass ----
    #pragma unroll
    for (int kh = 0; kh < 2; ++kh) {
        bf16x8 aw[4][4];
        #pragma unroll
        for (int ht = 0; ht < 4; ++ht)
            #pragma unroll
            for (int kt = 0; kt < 4; ++kt)
                aw[ht][kt] = *reinterpret_cast<const bf16x8*>(
                    W1p + (size_t)(ht * 16 + lr) * KDIM + (kh * 4 + kt) * 32 + lg * 8);
        #pragma unroll
        for (int kt = 0; kt < 4; ++kt) {
            int kk = (kh * 4 + kt) * 32 + lg * 8;
            bf16x8 xb[4];
            #pragma unroll
            for (int mt = 0; mt < 4; ++mt) {
                int m = mt * 16 + lr;
                int soff = (m * KDIM + kk) ^ ((m & 7) << 3);
                xb[mt] = *reinterpret_cast<const bf16x8*>(&xls[soff]);
            }
            #pragma unroll
            for (int ht = 0; ht < 4; ++ht)
                #pragma unroll
                for (int mt = 0; mt < 4; ++mt)
                    acc[ht][mt] = __builtin_amdgcn_mfma_f32_16x16x32_bf16(aw[ht][kt], xb[mt], acc[ht][mt], 0, 0, 0);
        }
    }

    // ---- bias + SiLU -> ACT buffer (no barrier needed before writes: separate buffer) ----
    #pragma unroll
    for (int ht = 0; ht < 4; ++ht) {
        int h0 = w * 64 + ht * 16 + lg * 4;
        f32x4 b1v = *reinterpret_cast<const f32x4*>(&b1[t * HDIM + h0]);
        #pragma unroll
        for (int mt = 0; mt < 4; ++mt) {
            int m = mt * 16 + lr;
            u16x4 o;
            #pragma unroll
            for (int r4 = 0; r4 < 4; ++r4) {
                float z = acc[ht][mt][r4] + b1v[r4];
                float s = z / (1.f + __expf(-z));
                o[r4] = f2b(s);
            }
            int soff = (m * HDIM + h0) ^ ((m & 7) << 3);
            *reinterpret_cast<u16x4*>(&als[soff]) = o;
        }
    }

    // ---- preload GEMM2 W fragments + epilogue node ids while waiting at barrier ----
    const unsigned short* W2p = W2T + ((size_t)t * DDIM + w * 32) * HDIM;
    bf16x8 aw2[2][8];
    #pragma unroll
    for (int dt = 0; dt < 2; ++dt)
        #pragma unroll
        for (int kt = 0; kt < 8; ++kt)
            aw2[dt][kt] = *reinterpret_cast<const bf16x8*>(
                W2p + (size_t)(dt * 16 + lr) * HDIM + kt * 32 + lg * 8);
    int nd[4];
    #pragma unroll
    for (int mt = 0; mt < 4; ++mt) {
        int p = row0 + mt * 16 + lr;
        nd[mt] = perm[p < N_NODES ? p : N_NODES - 1];
    }
    __syncthreads();

    // ---- GEMM2 ----
    f32x4 acc2[2][4];
    #pragma unroll
    for (int dt = 0; dt < 2; ++dt)
        #pragma unroll
        for (int mt = 0; mt < 4; ++mt)
            acc2[dt][mt] = (f32x4){0.f, 0.f, 0.f, 0.f};
    #pragma unroll
    for (int kt = 0; kt < 8; ++kt) {
        int kk = kt * 32 + lg * 8;
        bf16x8 ab[4];
        #pragma unroll
        for (int mt = 0; mt < 4; ++mt) {
            int m = mt * 16 + lr;
            int soff = (m * HDIM + kk) ^ ((m & 7) << 3);
            ab[mt] = *reinterpret_cast<const bf16x8*>(&als[soff]);
        }
        #pragma unroll
        for (int dt = 0; dt < 2; ++dt)
            #pragma unroll
            for (int mt = 0; mt < 4; ++mt)
                acc2[dt][mt] = __builtin_amdgcn_mfma_f32_16x16x32_bf16(aw2[dt][kt], ab[mt], acc2[dt][mt], 0, 0, 0);
    }

    // ---- epilogue: +b2, float4 scatter ----
    #pragma unroll
    for (int dt = 0; dt < 2; ++dt) {
        int d0 = w * 32 + dt * 16 + lg * 4;
        f32x4 b2v = *reinterpret_cast<const f32x4*>(&b2[t * DDIM + d0]);
        #pragma unroll
        for (int mt = 0; mt < 4; ++mt) {
            int p = row0 + mt * 16 + lr;
            if (p < segend) {
                f32x4 v = acc2[dt][mt] + b2v;
                *reinterpret_cast<f32x4*>(&dh[(size_t)nd[mt] * DDIM + d0]) = v;
            }
        }
    }
}

extern "C" void kernel_launch(void* const* d_in, const int* in_sizes, int n_in,
                              void* d_out, int out_size, void* d_ws, size_t ws_size,
                              hipStream_t stream) {
    const float* h   = (const float*)d_in[0];
    const float* msg = (const float*)d_in[1];
    const int*   ids = (const int*)d_in[2];
    const float* W1  = (const float*)d_in[3];
    const float* b1  = (const float*)d_in[4];
    const float* W2  = (const float*)d_in[5];
    const float* b2  = (const float*)d_in[6];
    float* dh = (float*)d_out;

    char* ws = (char*)d_ws;
    int* meta  = (int*)ws;                                   // 128 B
    int* perm  = (int*)(ws + 128);                           // 1 MB
    int* bcnt  = (int*)(ws + 128 + (size_t)N_NODES * 4);     // 16 KB
    int* gbase = bcnt + NTYPE * NB;                          // 16 KB
    unsigned short* W1T = (unsigned short*)(gbase + NTYPE * NB);
    unsigned short* W2T = W1T + (size_t)NTYPE * HDIM * KDIM;

    k_prep_hist<<<NB + 256, 256, 0, stream>>>(ids, W1, W2, bcnt, W1T, W2T);
    k_scan<<<1, 1024, 0, stream>>>(bcnt, gbase, meta);
    k_scatter<<<NB, 256, 0, stream>>>(ids, gbase, perm);
    k_mlp<<<N_NODES / BM + NTYPE, 256, 0, stream>>>(h, msg, b1, b2, meta, perm, W1T, W2T, dh);
}

// Round 4
// 446.141 us; speedup vs baseline: 1.9947x; 1.0005x over previous
//
#include <hip/hip_runtime.h>
#include <hip/hip_bf16.h>
#include <stdint.h>

#define N_NODES 262144
#define DDIM 128      // embed dim
#define KDIM 256      // 2*D concat input
#define HDIM 256      // hidden
#define NTYPE 4
#define BM 64         // nodes per MLP block
#define NB 1024       // N/256 histogram blocks

typedef float  f32x4  __attribute__((ext_vector_type(4)));
typedef short  bf16x8 __attribute__((ext_vector_type(8)));
typedef unsigned short u16x4 __attribute__((ext_vector_type(4)));

// meta layout: [4..7]=seg off[t], [8]=N, [9..12]=tile off[t], [13]=total tiles

__device__ __forceinline__ unsigned short f2b(float v) {
    unsigned int u = __builtin_bit_cast(unsigned int, v);
    u += 0x7FFFu + ((u >> 16) & 1u);
    return (unsigned short)(u >> 16);
}

// ---------------- K1: fused per-block histogram + weight convert/transpose ----------------
__global__ void k_prep_hist(const int* __restrict__ ids,
                            const float* __restrict__ W1, const float* __restrict__ W2,
                            int* __restrict__ bcnt,
                            unsigned short* __restrict__ W1T, unsigned short* __restrict__ W2T) {
    __shared__ int cnt[NTYPE];
    if (blockIdx.x < NB) {
        int tid = threadIdx.x, lane = tid & 63;
        if (tid < NTYPE) cnt[tid] = 0;
        __syncthreads();
        int t = ids[blockIdx.x * 256 + tid];
        #pragma unroll
        for (int tt = 0; tt < NTYPE; ++tt) {
            unsigned long long m = __ballot(t == tt);
            if (lane == 0) atomicAdd(&cnt[tt], (int)__popcll(m));
        }
        __syncthreads();
        if (tid < NTYPE) bcnt[tid * NB + blockIdx.x] = cnt[tid];
    } else {
        int tid = (blockIdx.x - NB) * 256 + threadIdx.x;
        const int stride = 256 * 256;
        const int n1 = NTYPE * HDIM * KDIM;   // W1T[t][h][k] = W1[t][k][h]
        for (int i = tid; i < n1; i += stride) {
            int t = i / (HDIM * KDIM);
            int rem = i % (HDIM * KDIM);
            int hh = rem / KDIM;
            int k  = rem % KDIM;
            W1T[i] = f2b(W1[((size_t)t * KDIM + k) * HDIM + hh]);
        }
        const int n2 = NTYPE * DDIM * HDIM;   // W2T[t][d][k] = W2[t][k][d]
        for (int i = tid; i < n2; i += stride) {
            int t = i / (DDIM * HDIM);
            int rem = i % (DDIM * HDIM);
            int d = rem / HDIM;
            int k = rem % HDIM;
            W2T[i] = f2b(W2[((size_t)t * HDIM + k) * DDIM + d]);
        }
    }
}

// ---------------- K2: scan per-block counts -> per-block bases + meta ----------------
__global__ __launch_bounds__(1024) void k_scan(const int* __restrict__ bcnt,
                                               int* __restrict__ gbase, int* __restrict__ meta) {
    __shared__ int wpart[16];
    __shared__ int ttot[NTYPE + 1];
    int tid = threadIdx.x, lane = tid & 63, wv = tid >> 6;
    if (tid == 0) ttot[0] = 0;
    for (int t = 0; t < NTYPE; ++t) {
        int v = bcnt[t * NB + tid];
        int s = v;
        #pragma unroll
        for (int d = 1; d < 64; d <<= 1) {
            int u = __shfl_up(s, d, 64);
            if (lane >= d) s += u;
        }
        if (lane == 63) wpart[wv] = s;
        __syncthreads();
        if (tid == 0) {
            int a = 0;
            for (int w = 0; w < 16; ++w) { int x = wpart[w]; wpart[w] = a; a += x; }
            ttot[t + 1] = ttot[t] + a;
        }
        __syncthreads();
        gbase[t * NB + tid] = ttot[t] + wpart[wv] + (s - v);
        __syncthreads();
    }
    if (tid == 0) {
        int off = 0, toff = 0;
        for (int t = 0; t < NTYPE; ++t) {
            int c = ttot[t + 1] - ttot[t];
            meta[4 + t] = off;
            meta[9 + t] = toff;
            off  += c;
            toff += (c + BM - 1) / BM;
        }
        meta[8]  = off;    // == N (seg-end for t=3)
        meta[13] = toff;   // total tiles
    }
}

// ---------------- K3: rank-based scatter (no global atomics) ----------------
__global__ void k_scatter(const int* __restrict__ ids, const int* __restrict__ gbase,
                          int* __restrict__ perm) {
    __shared__ int wb[4][NTYPE];
    int tid = threadIdx.x, lane = tid & 63, wv = tid >> 6;
    int i = blockIdx.x * 256 + tid;
    int t = ids[i];
    #pragma unroll
    for (int tt = 0; tt < NTYPE; ++tt) {
        unsigned long long m = __ballot(t == tt);
        if (lane == 0) wb[wv][tt] = (int)__popcll(m);
    }
    __syncthreads();
    if (tid < NTYPE) {
        int a = 0;
        for (int w = 0; w < 4; ++w) { int x = wb[w][tid]; wb[w][tid] = a; a += x; }
    }
    __syncthreads();
    #pragma unroll
    for (int tt = 0; tt < NTYPE; ++tt) {
        unsigned long long m = __ballot(t == tt);
        if (t == tt) {
            int rank = (int)__popcll(m & ((1ull << lane) - 1ull));
            perm[gbase[tt * NB + blockIdx.x] + wb[wv][tt] + rank] = i;
        }
    }
}

// ---------------- K4: fused 2-layer MLP ----------------
// 256 thr / 4 waves, BM=64 nodes/block. Swapped-operand MFMA: D[row=4-consec h|d, col=m].
// Register-lean: single shared 32KB X/ACT LDS buffer, in-loop fragment loads (no
// cross-phase preloads), scalarized block-uniform addressing. Target <=128 total
// regs/wave (incl. AGPR accumulators) -> 4 waves/SIMD -> 4 blocks/CU resident.
__global__ __launch_bounds__(256, 4) void k_mlp(
        const float* __restrict__ hbuf, const float* __restrict__ mbuf,
        const float* __restrict__ b1,   const float* __restrict__ b2,
        const int* __restrict__ meta,   const int* __restrict__ perm,
        const unsigned short* __restrict__ W1T, const unsigned short* __restrict__ W2T,
        float* __restrict__ dh) {
    __shared__ unsigned short lsb[BM * KDIM];  // 32 KB: X tile, then activations

    int b = blockIdx.x;
    if (b >= meta[13]) return;
    int t = 0;
    #pragma unroll
    for (int tt = 1; tt < NTYPE; ++tt) t += (b >= meta[9 + tt]);
    t = __builtin_amdgcn_readfirstlane(t);
    int row0   = __builtin_amdgcn_readfirstlane(meta[4 + t] + (b - meta[9 + t]) * BM);
    int segend = __builtin_amdgcn_readfirstlane(meta[4 + t + 1]);

    int tid = threadIdx.x, lane = tid & 63, w = tid >> 6;
    int lr = lane & 15, lg = lane >> 4;

    // ---- stage X = bf16(concat(h,msg)) into swizzled LDS; wave-uniform row ids in SGPRs ----
    int c = lane;
    #pragma unroll
    for (int j = 0; j < 16; ++j) {
        int r = w + 4 * j;
        int p = row0 + r;
        int node = __builtin_amdgcn_readfirstlane(perm[p < N_NODES ? p : N_NODES - 1]);
        const float* src = (c < 32) ? (hbuf + (size_t)node * DDIM + c * 4)
                                    : (mbuf + (size_t)node * DDIM + (c - 32) * 4);
        float4 v = *reinterpret_cast<const float4*>(src);
        u16x4 o;
        o.x = f2b(v.x); o.y = f2b(v.y); o.z = f2b(v.z); o.w = f2b(v.w);
        int soff = (r * KDIM + c * 4) ^ ((r & 7) << 3);
        *reinterpret_cast<u16x4*>(&lsb[soff]) = o;
    }
    __syncthreads();

    // ---- GEMM1: D1[h][m], wave w owns h in [64w, 64w+64) ----
    f32x4 acc[4][4];
    #pragma unroll
    for (int ht = 0; ht < 4; ++ht)
        #pragma unroll
        for (int mt = 0; mt < 4; ++mt)
            acc[ht][mt] = (f32x4){0.f, 0.f, 0.f, 0.f};

    const unsigned short* W1p = W1T + ((size_t)t * HDIM + w * 64) * KDIM;
    #pragma unroll
    for (int kt = 0; kt < KDIM / 32; ++kt) {
        int kk = kt * 32 + lg * 8;
        bf16x8 aw[4], xb[4];
        #pragma unroll
        for (int ht = 0; ht < 4; ++ht)
            aw[ht] = *reinterpret_cast<const bf16x8*>(W1p + (size_t)(ht * 16 + lr) * KDIM + kk);
        #pragma unroll
        for (int mt = 0; mt < 4; ++mt) {
            int m = mt * 16 + lr;
            int soff = (m * KDIM + kk) ^ ((m & 7) << 3);
            xb[mt] = *reinterpret_cast<const bf16x8*>(&lsb[soff]);
        }
        #pragma unroll
        for (int ht = 0; ht < 4; ++ht)
            #pragma unroll
            for (int mt = 0; mt < 4; ++mt)
                acc[ht][mt] = __builtin_amdgcn_mfma_f32_16x16x32_bf16(aw[ht], xb[mt], acc[ht][mt], 0, 0, 0);
    }
    __syncthreads();   // all X reads done before ACT overwrite

    // ---- bias + SiLU -> same LDS buffer (u16x4 writes; lane holds 4 consecutive h) ----
    #pragma unroll
    for (int ht = 0; ht < 4; ++ht) {
        int h0 = w * 64 + ht * 16 + lg * 4;
        f32x4 b1v = *reinterpret_cast<const f32x4*>(&b1[t * HDIM + h0]);
        #pragma unroll
        for (int mt = 0; mt < 4; ++mt) {
            int m = mt * 16 + lr;
            u16x4 o;
            #pragma unroll
            for (int r4 = 0; r4 < 4; ++r4) {
                float z = acc[ht][mt][r4] + b1v[r4];
                float s = z / (1.f + __expf(-z));
                o[r4] = f2b(s);
            }
            int soff = (m * HDIM + h0) ^ ((m & 7) << 3);
            *reinterpret_cast<u16x4*>(&lsb[soff]) = o;
        }
    }
    __syncthreads();

    // ---- GEMM2: D2[d][m], wave w owns d in [32w, 32w+32); in-loop W2 loads ----
    f32x4 acc2[2][4];
    #pragma unroll
    for (int dt = 0; dt < 2; ++dt)
        #pragma unroll
        for (int mt = 0; mt < 4; ++mt)
            acc2[dt][mt] = (f32x4){0.f, 0.f, 0.f, 0.f};

    const unsigned short* W2p = W2T + ((size_t)t * DDIM + w * 32) * HDIM;
    #pragma unroll
    for (int kt = 0; kt < HDIM / 32; ++kt) {
        int kk = kt * 32 + lg * 8;
        bf16x8 aw2[2], ab[4];
        #pragma unroll
        for (int dt = 0; dt < 2; ++dt)
            aw2[dt] = *reinterpret_cast<const bf16x8*>(W2p + (size_t)(dt * 16 + lr) * HDIM + kk);
        #pragma unroll
        for (int mt = 0; mt < 4; ++mt) {
            int m = mt * 16 + lr;
            int soff = (m * HDIM + kk) ^ ((m & 7) << 3);
            ab[mt] = *reinterpret_cast<const bf16x8*>(&lsb[soff]);
        }
        #pragma unroll
        for (int dt = 0; dt < 2; ++dt)
            #pragma unroll
            for (int mt = 0; mt < 4; ++mt)
                acc2[dt][mt] = __builtin_amdgcn_mfma_f32_16x16x32_bf16(aw2[dt], ab[mt], acc2[dt][mt], 0, 0, 0);
    }

    // ---- epilogue: +b2, float4 scatter ----
    int nd[4];
    #pragma unroll
    for (int mt = 0; mt < 4; ++mt) {
        int p = row0 + mt * 16 + lr;
        nd[mt] = perm[p < N_NODES ? p : N_NODES - 1];
    }
    #pragma unroll
    for (int dt = 0; dt < 2; ++dt) {
        int d0 = w * 32 + dt * 16 + lg * 4;
        f32x4 b2v = *reinterpret_cast<const f32x4*>(&b2[t * DDIM + d0]);
        #pragma unroll
        for (int mt = 0; mt < 4; ++mt) {
            int p = row0 + mt * 16 + lr;
            if (p < segend) {
                f32x4 v = acc2[dt][mt] + b2v;
                *reinterpret_cast<f32x4*>(&dh[(size_t)nd[mt] * DDIM + d0]) = v;
            }
        }
    }
}

extern "C" void kernel_launch(void* const* d_in, const int* in_sizes, int n_in,
                              void* d_out, int out_size, void* d_ws, size_t ws_size,
                              hipStream_t stream) {
    const float* h   = (const float*)d_in[0];
    const float* msg = (const float*)d_in[1];
    const int*   ids = (const int*)d_in[2];
    const float* W1  = (const float*)d_in[3];
    const float* b1  = (const float*)d_in[4];
    const float* W2  = (const float*)d_in[5];
    const float* b2  = (const float*)d_in[6];
    float* dh = (float*)d_out;

    char* ws = (char*)d_ws;
    int* meta  = (int*)ws;                                   // 128 B
    int* perm  = (int*)(ws + 128);                           // 1 MB
    int* bcnt  = (int*)(ws + 128 + (size_t)N_NODES * 4);     // 16 KB
    int* gbase = bcnt + NTYPE * NB;                          // 16 KB
    unsigned short* W1T = (unsigned short*)(gbase + NTYPE * NB);
    unsigned short* W2T = W1T + (size_t)NTYPE * HDIM * KDIM;

    k_prep_hist<<<NB + 256, 256, 0, stream>>>(ids, W1, W2, bcnt, W1T, W2T);
    k_scan<<<1, 1024, 0, stream>>>(bcnt, gbase, meta);
    k_scatter<<<NB, 256, 0, stream>>>(ids, gbase, perm);
    k_mlp<<<N_NODES / BM + NTYPE, 256, 0, stream>>>(h, msg, b1, b2, meta, perm, W1T, W2T, dh);
}